// Round 11
// baseline (756.420 us; speedup 1.0000x reference)
//
#include <hip/hip_runtime.h>
#include <cstdint>
#include <cstddef>

using u16 = unsigned short;
using f32x4 = __attribute__((ext_vector_type(4))) float;
using bf8   = __attribute__((ext_vector_type(8))) short;   // 8 bf16 in 4 VGPRs
using u32x4 = __attribute__((ext_vector_type(4))) unsigned;

#define DEVFN __device__ __forceinline__

constexpr int BB  = 2;
constexpr int LQ  = 2048;
constexpr int LKV = 4096;
constexpr int DD  = 2048;
constexpr int NH  = 16;
constexpr int HDm = 128;
constexpr float ATTN_SCALE = 0.08838834764831845f;  // 128^-0.5
constexpr float LN_EPS = 1e-6f;
// softmax fixed shift: LN guarantees |s| <= ||q*scale||*||k|| = 1*sqrt(128) ~ 11.4
constexpr float LOG2E  = 1.4426950408889634f;
constexpr float SHIFT2 = 17.312340490667562f;       // 12.0 * log2(e)

DEVFN u16 f2bf(float f) {
  unsigned u = __builtin_bit_cast(unsigned, f);
  u += 0x7fffu + ((u >> 16) & 1u);          // RNE
  return (u16)(u >> 16);
}
DEVFN float bf2f(u16 h) { return __builtin_bit_cast(float, (unsigned)h << 16); }
DEVFN f32x4 mfma16(bf8 a, bf8 b, f32x4 c) {
  return __builtin_amdgcn_mfma_f32_16x16x32_bf16(a, b, c, 0, 0, 0);
}
// async global->LDS, 16B/lane, lane i lands at lds + i*16 (wave-uniform lds base)
DEVFN void gl16(const void* g, void* l) {
  __builtin_amdgcn_global_load_lds(
      (const __attribute__((address_space(1))) void*)g,
      (__attribute__((address_space(3))) void*)l, 16, 0, 0);
}
DEVFN void barrier_hard() {                 // raw barrier + scheduler fence
  __builtin_amdgcn_s_barrier();
  __builtin_amdgcn_sched_barrier(0);
}

// ---------------- fused f32 -> bf16 convert, ALL segments in one launch ----
struct C6 {
  const float4* s[6];
  ushort4* d[6];
  unsigned off[7];                          // prefix sums in float4 units
};
__global__ __launch_bounds__(256) void k_cvt6(C6 a) {
  unsigned gi = blockIdx.x * 256 + threadIdx.x;
  if (gi >= a.off[6]) return;
  int seg = 0;
#pragma unroll
  for (int i = 1; i < 6; ++i) seg += (gi >= a.off[i]);
  unsigned j = gi - a.off[seg];
  float4 v = a.s[seg][j];
  ushort4 o;
  o.x = f2bf(v.x); o.y = f2bf(v.y); o.z = f2bf(v.z); o.w = f2bf(v.w);
  a.d[seg][j] = o;
}

// ---------------- bf16 NT GEMM: Y[M,N] = X[M,K] * W[N,K]^T + bias[N] -------
// (R6-verified) 128x128 tile, BK=64, 4 waves, gl16 staging + XOR swizzle.
// MODE: 1 = f32 out (nontemporal); 2 = bf16 + per-head LN;
//       3 = bf16 + per-head LN + ATTN_SCALE;
//       4 = bf16 TRANSPOSED per-head out -> Y[bh][hd][kv]  (fused V-transpose)
template <int MODE>
__global__ __launch_bounds__(256) void k_gemm_nt(const u16* __restrict__ X,
                                                 const u16* __restrict__ Wt,
                                                 const float* __restrict__ bias,
                                                 const float* __restrict__ lng,
                                                 const float* __restrict__ lnb,
                                                 void* __restrict__ Y,
                                                 int M, int N, int K) {
  __shared__ __align__(16) u16 Sh[2][128 * 64];   // As | Bs ; reused as T[128][128]
  __shared__ float Sm[2][128], Sq[2][128];
  u16* As = Sh[0];
  u16* Bs = Sh[1];
  const int tid = threadIdx.x;
  const int w = tid >> 6, l = tid & 63;
  const int m0 = blockIdx.x * 128, n0 = blockIdx.y * 128;
  const int wr = w >> 1, wc = w & 1;
  const int lr = l & 15, lk = (l >> 4) * 8;
  const int rsw = (l & 7) << 3;               // read-side swizzle (u16 units)
  const int srow = l >> 3;
  const int scb = (l & 7) * 16;
  f32x4 acc[4][4] = {};

  for (int k0 = 0; k0 < K; k0 += 64) {
#pragma unroll
    for (int i = 0; i < 4; ++i) {
      int rbase = w * 32 + i * 8;
      int row = rbase + srow;
      int cb = scb ^ ((row & 7) << 4);        // inverse-swizzled source col (bytes)
      gl16((const char*)&X[(size_t)(m0 + row) * K + k0] + cb, &As[rbase * 64]);
      gl16((const char*)&Wt[(size_t)(n0 + row) * K + k0] + cb, &Bs[rbase * 64]);
    }
    __syncthreads();
    bf8 af[4][2], bfr[4][2];
#pragma unroll
    for (int mi = 0; mi < 4; ++mi)
#pragma unroll
      for (int kk = 0; kk < 2; ++kk)
        af[mi][kk] = *(const bf8*)&As[(wr * 64 + mi * 16 + lr) * 64 + ((kk * 32 + lk) ^ rsw)];
#pragma unroll
    for (int ni = 0; ni < 4; ++ni)
#pragma unroll
      for (int kk = 0; kk < 2; ++kk)
        bfr[ni][kk] = *(const bf8*)&Bs[(wc * 64 + ni * 16 + lr) * 64 + ((kk * 32 + lk) ^ rsw)];
#pragma unroll
    for (int kk = 0; kk < 2; ++kk)
#pragma unroll
      for (int mi = 0; mi < 4; ++mi)
#pragma unroll
        for (int ni = 0; ni < 4; ++ni)
          acc[mi][ni] = mfma16(af[mi][kk], bfr[ni][kk], acc[mi][ni]);
    __syncthreads();
  }
  const int lrg = (l >> 4) * 4;

  // bias (pre-LN, matching reference: LN(x@W^T + b))
  float bv[4];
#pragma unroll
  for (int ni = 0; ni < 4; ++ni) bv[ni] = bias[n0 + wc * 64 + ni * 16 + lr];
#pragma unroll
  for (int mi = 0; mi < 4; ++mi)
#pragma unroll
    for (int ni = 0; ni < 4; ++ni)
#pragma unroll
      for (int r = 0; r < 4; ++r) acc[mi][ni][r] += bv[ni];

  if constexpr (MODE == 2 || MODE == 3) {
#pragma unroll
    for (int mi = 0; mi < 4; ++mi) {
#pragma unroll
      for (int r = 0; r < 4; ++r) {
        float ps = 0.f, pq = 0.f;
#pragma unroll
        for (int ni = 0; ni < 4; ++ni) {
          float v = acc[mi][ni][r];
          ps += v; pq += v * v;
        }
#pragma unroll
        for (int m = 1; m < 16; m <<= 1) {
          ps += __shfl_xor(ps, m);
          pq += __shfl_xor(pq, m);
        }
        if (lr == 0) {
          int rl = wr * 64 + mi * 16 + lrg + r;
          Sm[wc][rl] = ps; Sq[wc][rl] = pq;
        }
      }
    }
    __syncthreads();
    float gv[4], bbv[4];
#pragma unroll
    for (int ni = 0; ni < 4; ++ni) {
      int c = wc * 64 + ni * 16 + lr;          // col within head (n-tile aligned)
      gv[ni] = lng[c]; bbv[ni] = lnb[c];
    }
#pragma unroll
    for (int mi = 0; mi < 4; ++mi)
#pragma unroll
      for (int r = 0; r < 4; ++r) {
        int rl = wr * 64 + mi * 16 + lrg + r;
        float mean = (Sm[0][rl] + Sm[1][rl]) * (1.f / 128.f);
        float var  = (Sq[0][rl] + Sq[1][rl]) * (1.f / 128.f) - mean * mean;
        float rs = rsqrtf(var + LN_EPS);
#pragma unroll
        for (int ni = 0; ni < 4; ++ni) {
          float o = (acc[mi][ni][r] - mean) * rs * gv[ni] + bbv[ni];
          if (MODE == 3) o *= ATTN_SCALE;
          acc[mi][ni][r] = o;
        }
      }
  }

  if constexpr (MODE == 4) {
    u16* T = &Sh[0][0];                        // 128*128 u16 = 32 KB
#pragma unroll
    for (int mi = 0; mi < 4; ++mi)
#pragma unroll
      for (int ni = 0; ni < 4; ++ni)
#pragma unroll
        for (int r = 0; r < 4; ++r) {
          int mrow = wr * 64 + mi * 16 + lrg + r;
          int ncol = wc * 64 + ni * 16 + lr;
          T[mrow * 128 + (ncol ^ ((mrow & 7) << 3))] = f2bf(acc[mi][ni][r]);
        }
    __syncthreads();
    int hd = tid >> 1, half = tid & 1;
    int bq = m0 >> 12;                          // m = b*LKV + kv, LKV=4096
    int kvb = (m0 & (LKV - 1)) + half * 64;
    int hh = n0 >> 7;                           // n-tile == head
    u16* vout = (u16*)Y + ((size_t)(bq * NH + hh) * HDm + hd) * LKV + kvb;
#pragma unroll
    for (int j8 = 0; j8 < 8; ++j8) {
      u16 tmp[8] __attribute__((aligned(16)));
#pragma unroll
      for (int j = 0; j < 8; ++j) {
        int kv = half * 64 + j8 * 8 + j;
        tmp[j] = T[kv * 128 + (hd ^ ((kv & 7) << 3))];
      }
      *(int4*)&vout[j8 * 8] = *(const int4*)tmp;
    }
    return;
  }

#pragma unroll
  for (int ni = 0; ni < 4; ++ni) {
    int n = n0 + wc * 64 + ni * 16 + lr;
#pragma unroll
    for (int mi = 0; mi < 4; ++mi) {
      int mb = m0 + wr * 64 + mi * 16 + lrg;
#pragma unroll
      for (int r = 0; r < 4; ++r) {
        float v = acc[mi][ni][r];
        if constexpr (MODE == 1)
          __builtin_nontemporal_store(v, &((float*)Y)[(size_t)(mb + r) * N + n]);
        else
          ((u16*)Y)[(size_t)(mb + r) * N + n] = f2bf(v);
      }
    }
  }
}

// ---------------- fused attention ------------------------------------------
// 512 threads / 8 waves, q-tile 128. Pass A: kv-tile 64, FOUR 16KB buffers,
// 2-deep prefetch, vmcnt(2) (never drain to 0 — T4). Pass B: kv-tile 64 dbuf,
// P in registers, pf via shfl, Wout f32x4 nontemporal; vmcnt(16) retires
// prev-iter stores + this-iter loads only (FIFO: 4 loads older than 16 stores).
__global__ __launch_bounds__(512, 4) void k_attn(const u16* __restrict__ Qp,
                                                 const u16* __restrict__ Kp,
                                                 const u16* __restrict__ Vt,
                                                 float* __restrict__ Wout,
                                                 u16* __restrict__ AO) {
  const int g = blockIdx.x;                 // 512 blocks, 8 XCDs, 64 each
  const int work = (g & 7) * 64 + (g >> 3);
  const int bh = work >> 4;
  const int b = bh >> 4, h = bh & 15;
  const int q0 = (work & 15) * 128;
  const int tid = threadIdx.x, w = tid >> 6, l = tid & 63;
  const int lr = l & 15, lk = (l >> 4) * 8;
  const int gq = l >> 4;                    // lane group 0..3 (kv sub-quad)
  const int rsw = (l & 7) << 3;             // read swizzle, u16 units
  __shared__ __align__(16) u16 Ks[2][64 * 128];
  __shared__ __align__(16) u16 Vs[2][128 * 64];

  // hoist Q fragments (B-frag for swapped mfma: col = lr, 8 k-els at kc*32+lk)
  bf8 qf[4];
  {
    const u16* qb = &Qp[((size_t)b * LQ + q0 + w * 16 + lr) * DD + h * HDm];
#pragma unroll
    for (int kc = 0; kc < 4; ++kc) qf[kc] = *(const bf8*)(qb + kc * 32 + lk);
  }
  const u16* Kb = Kp + (size_t)b * LKV * DD + h * HDm;   // row stride DD
  const u16* Vb = Vt + (size_t)bh * HDm * LKV;           // row (hd) stride LKV

  // ---- staging helpers
  auto stageK64 = [&](u16* buf, int kv0) {    // 64 rows x 256 B, 2 gl16/wave
#pragma unroll
    for (int i = 0; i < 2; ++i) {
      int rbase = i * 32 + w * 4;
      int row = rbase + (l >> 4);
      int cb = ((l & 15) * 16) ^ ((row & 7) << 4);
      gl16((const char*)(Kb + (size_t)(kv0 + row) * DD) + cb, &buf[rbase * 128]);
    }
  };
  auto stageV = [&](int buf, int kv0) {       // 128 rows x 128 B
#pragma unroll
    for (int i = 0; i < 2; ++i) {
      int rbase = i * 64 + w * 8;
      int row = rbase + (l >> 3);
      int cb = ((l & 7) * 16) ^ ((row & 7) << 4);
      gl16((const char*)(Vb + (size_t)row * LKV + kv0) + cb, &Vs[buf][rbase * 64]);
    }
  };

  // ================= pass A: lane-local row sums, kv-tile 64, 4-buf ring ====
  u16* bufs[4] = {&Ks[0][0], &Ks[1][0], &Vs[0][0], &Vs[1][0]};
  float lsum = 0.f;
  stageK64(bufs[0], 0);
  stageK64(bufs[1], 64);
  asm volatile("s_waitcnt vmcnt(2)" ::: "memory");   // tile 0 staged, tile 1 flying
  barrier_hard();
  for (int tt = 0; tt < 64; tt += 4) {
#pragma unroll
    for (int u = 0; u < 4; ++u) {
      const int t = tt + u;
      const int tp = t + 2;
      // always issue 2 loads (clamped tile for tail -> uniform vmcnt count)
      stageK64(bufs[tp & 3], (tp < 64 ? tp : 63) * 64);
      const u16* kb = bufs[t & 3];
      f32x4 s4[4];
      __builtin_amdgcn_s_setprio(1);
#pragma unroll
      for (int ni = 0; ni < 4; ++ni) {
        s4[ni] = f32x4{0.f, 0.f, 0.f, 0.f};
#pragma unroll
        for (int kc = 0; kc < 4; ++kc) {
          bf8 kf = *(const bf8*)&kb[(ni * 16 + lr) * 128 + ((kc * 32 + lk) ^ rsw)];
          s4[ni] = mfma16(kf, qf[kc], s4[ni]);
        }
      }
      __builtin_amdgcn_s_setprio(0);
#pragma unroll
      for (int ni = 0; ni < 4; ++ni)
#pragma unroll
        for (int r = 0; r < 4; ++r)
          lsum += exp2f(fmaf(s4[ni][r], LOG2E, -SHIFT2));
      // retire tile t+1's loads; leave tile t+2's 2 loads in flight
      asm volatile("s_waitcnt vmcnt(2)" ::: "memory");
      barrier_hard();
    }
  }
  // lane lr holds partials of q-row lr; combine the 4 lane-groups
  lsum += __shfl_xor(lsum, 16);
  lsum += __shfl_xor(lsum, 32);
  const float cr = -(SHIFT2 + __log2f(lsum));   // exp2(s*log2e + cr) = p/sum

  // ================= pass B: weights + PV, kv-tile 64 =======================
  f32x4 oacc[8] = {};
  float* wq = Wout + ((size_t)bh * LQ + q0 + w * 16 + lr) * LKV;
  const int srcA = lr + ((gq & 1) << 5);
  const int srcB = srcA + 16;
  const bool hi = (gq >> 1) != 0;

  stageK64(&Ks[0][0], 0); stageV(0, 0);
  asm volatile("s_waitcnt vmcnt(0)" ::: "memory");
  barrier_hard();
  for (int t = 0; t < 64; ++t) {
    const int cur = t & 1;
    const int kv0 = t * 64;
    if (t < 63) { stageK64(&Ks[cur ^ 1][0], kv0 + 64); stageV(cur ^ 1, kv0 + 64); }
    // QK swapped: s[ni] rows = kv (ni*16 + 4*gq + r), col = q-row lr
    f32x4 s[4];
    __builtin_amdgcn_s_setprio(1);
#pragma unroll
    for (int ni = 0; ni < 4; ++ni) {
      s[ni] = f32x4{0.f, 0.f, 0.f, 0.f};
#pragma unroll
      for (int kc = 0; kc < 4; ++kc) {
        bf8 kf = *(const bf8*)&Ks[cur][(ni * 16 + lr) * 128 + ((kc * 32 + lk) ^ rsw)];
        s[ni] = mfma16(kf, qf[kc], s[ni]);
      }
    }
    __builtin_amdgcn_s_setprio(0);
    // normalized p: 4 contiguous kv per lane -> f32x4 nontemporal stores
    unsigned pk2[4][2];
#pragma unroll
    for (int ni = 0; ni < 4; ++ni) {
      float p0 = exp2f(fmaf(s[ni][0], LOG2E, cr));
      float p1 = exp2f(fmaf(s[ni][1], LOG2E, cr));
      float p2 = exp2f(fmaf(s[ni][2], LOG2E, cr));
      float p3 = exp2f(fmaf(s[ni][3], LOG2E, cr));
      f32x4 pv4 = {p0, p1, p2, p3};
      __builtin_nontemporal_store(pv4, (f32x4*)(wq + kv0 + ni * 16 + 4 * gq));
      pk2[ni][0] = (unsigned)f2bf(p0) | ((unsigned)f2bf(p1) << 16);
      pk2[ni][1] = (unsigned)f2bf(p2) | ((unsigned)f2bf(p3) << 16);
    }
    // assemble pf (A-frag of PV: q-row lr, 8 kv at kk*32+8*gq) via shfl + PV
#pragma unroll
    for (int kk = 0; kk < 2; ++kk) {
      unsigned xa0 = __shfl(pk2[2 * kk][0], srcA), xa1 = __shfl(pk2[2 * kk][1], srcA);
      unsigned ya0 = __shfl(pk2[2 * kk + 1][0], srcA), ya1 = __shfl(pk2[2 * kk + 1][1], srcA);
      unsigned xb0 = __shfl(pk2[2 * kk][0], srcB), xb1 = __shfl(pk2[2 * kk][1], srcB);
      unsigned yb0 = __shfl(pk2[2 * kk + 1][0], srcB), yb1 = __shfl(pk2[2 * kk + 1][1], srcB);
      u32x4 pf32 = { hi ? ya0 : xa0, hi ? ya1 : xa1, hi ? yb0 : xb0, hi ? yb1 : xb1 };
      bf8 pf = __builtin_bit_cast(bf8, pf32);
      __builtin_amdgcn_s_setprio(1);
#pragma unroll
      for (int c = 0; c < 8; ++c) {
        bf8 vf = *(const bf8*)&Vs[cur][(c * 16 + lr) * 64 + ((kk * 32 + lk) ^ rsw)];
        oacc[c] = mfma16(pf, vf, oacc[c]);
      }
      __builtin_amdgcn_s_setprio(0);
    }
    // FIFO: retire prev-iter's 16 stores + this iter's 4 loads; keep this
    // iter's 16 stores in flight (loads are OLDER than stores within an iter)
    asm volatile("s_waitcnt vmcnt(16)" ::: "memory");
    barrier_hard();
  }

  // epilogue: AO [B, Lq, D] bf16 (oacc rows q = 4*gq + r, cols hd = c*16+lr)
#pragma unroll
  for (int c = 0; c < 8; ++c)
#pragma unroll
    for (int r = 0; r < 4; ++r)
      AO[((size_t)b * LQ + q0 + w * 16 + 4 * gq + r) * DD + h * HDm + c * 16 + lr] =
          f2bf(oacc[c][r]);
}

// ---------------------------------------------------------------------------
extern "C" void kernel_launch(void* const* d_in, const int* in_sizes, int n_in,
                              void* d_out, int out_size, void* d_ws, size_t ws_size,
                              hipStream_t stream) {
  const float* hs   = (const float*)d_in[0];
  const float* cas  = (const float*)d_in[1];
  const float* q_w  = (const float*)d_in[2];
  const float* q_b  = (const float*)d_in[3];
  const float* k_w  = (const float*)d_in[4];
  const float* k_b  = (const float*)d_in[5];
  const float* v_w  = (const float*)d_in[6];
  const float* v_b  = (const float*)d_in[7];
  const float* o_w  = (const float*)d_in[8];
  const float* o_b  = (const float*)d_in[9];
  const float* qn_g = (const float*)d_in[10];
  const float* qn_b = (const float*)d_in[11];
  const float* kn_g = (const float*)d_in[12];
  const float* kn_b = (const float*)d_in[13];

  float* out_attn = (float*)d_out;
  float* out_w    = out_attn + (size_t)BB * LQ * DD;

  constexpr size_t SZ_Q  = (size_t)BB * LQ * DD * 2;
  constexpr size_t SZ_KV = (size_t)BB * LKV * DD * 2;
  constexpr size_t SZ_W  = (size_t)DD * DD * 2;
  char* p = (char*)d_ws;
  u16* hsb  = (u16*)p;              p += SZ_Q;
  u16* casb = (u16*)p;              p += SZ_KV;
  u16* qwb  = (u16*)p;              p += SZ_W;
  u16* kwb  = (u16*)p;              p += SZ_W;
  u16* vwb  = (u16*)p;              p += SZ_W;
  u16* owb  = (u16*)p;              p += SZ_W;
  u16* Qp   = (u16*)p;              p += SZ_Q;
  u16* Kp   = (u16*)p;              p += SZ_KV;
  u16* Vtp  = (u16*)p;              p += SZ_KV;
  u16* AO   = (u16*)p;              p += SZ_Q;

  // 1) all f32->bf16 conversions in one launch
  constexpr unsigned HS4 = BB * LQ * DD / 4;
  constexpr unsigned CAS4 = BB * LKV * DD / 4;
  constexpr unsigned W4 = DD * DD / 4;
  C6 a;
  a.s[0] = (const float4*)hs;  a.d[0] = (ushort4*)hsb;
  a.s[1] = (const float4*)cas; a.d[1] = (ushort4*)casb;
  a.s[2] = (const float4*)q_w; a.d[2] = (ushort4*)qwb;
  a.s[3] = (const float4*)k_w; a.d[3] = (ushort4*)kwb;
  a.s[4] = (const float4*)v_w; a.d[4] = (ushort4*)vwb;
  a.s[5] = (const float4*)o_w; a.d[5] = (ushort4*)owb;
  a.off[0] = 0;
  a.off[1] = HS4;
  a.off[2] = HS4 + CAS4;
  a.off[3] = HS4 + CAS4 + W4;
  a.off[4] = HS4 + CAS4 + 2 * W4;
  a.off[5] = HS4 + CAS4 + 3 * W4;
  a.off[6] = HS4 + CAS4 + 4 * W4;
  k_cvt6<<<dim3((a.off[6] + 255) / 256), dim3(256), 0, stream>>>(a);

  // 2) projections; LN fused for Q (with ATTN_SCALE) and K; V writes transposed
  k_gemm_nt<3><<<dim3(BB * LQ / 128, DD / 128), dim3(256), 0, stream>>>(
      hsb, qwb, q_b, qn_g, qn_b, Qp, BB * LQ, DD, DD);
  k_gemm_nt<2><<<dim3(BB * LKV / 128, DD / 128), dim3(256), 0, stream>>>(
      casb, kwb, k_b, kn_g, kn_b, Kp, BB * LKV, DD, DD);
  k_gemm_nt<4><<<dim3(BB * LKV / 128, DD / 128), dim3(256), 0, stream>>>(
      casb, vwb, v_b, nullptr, nullptr, Vtp, BB * LKV, DD, DD);

  // 3) fused attention (pass A sums + pass B weights/PV)
  k_attn<<<dim3(LQ / 128 * BB * NH), dim3(512), 0, stream>>>(Qp, Kp, Vtp, out_w, AO);

  // 4) O projection -> fp32 into d_out
  k_gemm_nt<1><<<dim3(BB * LQ / 128, DD / 128), dim3(256), 0, stream>>>(
      AO, owb, o_b, nullptr, nullptr, out_attn, BB * LQ, DD, DD);
}

// Round 12
// 742.992 us; speedup vs baseline: 1.0181x; 1.0181x over previous
//
#include <hip/hip_runtime.h>
#include <cstdint>
#include <cstddef>

using u16 = unsigned short;
using f32x4 = __attribute__((ext_vector_type(4))) float;
using bf8   = __attribute__((ext_vector_type(8))) short;   // 8 bf16 in 4 VGPRs
using u32x4 = __attribute__((ext_vector_type(4))) unsigned;

#define DEVFN __device__ __forceinline__

constexpr int BB  = 2;
constexpr int LQ  = 2048;
constexpr int LKV = 4096;
constexpr int DD  = 2048;
constexpr int NH  = 16;
constexpr int HDm = 128;
constexpr float ATTN_SCALE = 0.08838834764831845f;  // 128^-0.5
constexpr float LN_EPS = 1e-6f;
// softmax fixed shift: LN guarantees |s| <= ||q*scale||*||k|| = 1*sqrt(128) ~ 11.4
constexpr float LOG2E  = 1.4426950408889634f;
constexpr float SHIFT2 = 17.312340490667562f;       // 12.0 * log2(e)

DEVFN u16 f2bf(float f) {
  unsigned u = __builtin_bit_cast(unsigned, f);
  u += 0x7fffu + ((u >> 16) & 1u);          // RNE
  return (u16)(u >> 16);
}
DEVFN float bf2f(u16 h) { return __builtin_bit_cast(float, (unsigned)h << 16); }
DEVFN f32x4 mfma16(bf8 a, bf8 b, f32x4 c) {
  return __builtin_amdgcn_mfma_f32_16x16x32_bf16(a, b, c, 0, 0, 0);
}
// async global->LDS, 16B/lane, lane i lands at lds + i*16 (wave-uniform lds base)
DEVFN void gl16(const void* g, void* l) {
  __builtin_amdgcn_global_load_lds(
      (const __attribute__((address_space(1))) void*)g,
      (__attribute__((address_space(3))) void*)l, 16, 0, 0);
}
DEVFN void barrier_hard() {                 // raw barrier + scheduler fence
  __builtin_amdgcn_s_barrier();
  __builtin_amdgcn_sched_barrier(0);
}

// ---------------- fused f32 -> bf16 convert, ALL segments in one launch ----
struct C6 {
  const float4* s[6];
  ushort4* d[6];
  unsigned off[7];                          // prefix sums in float4 units
};
__global__ __launch_bounds__(256) void k_cvt6(C6 a) {
  unsigned gi = blockIdx.x * 256 + threadIdx.x;
  if (gi >= a.off[6]) return;
  int seg = 0;
#pragma unroll
  for (int i = 1; i < 6; ++i) seg += (gi >= a.off[i]);
  unsigned j = gi - a.off[seg];
  float4 v = a.s[seg][j];
  ushort4 o;
  o.x = f2bf(v.x); o.y = f2bf(v.y); o.z = f2bf(v.z); o.w = f2bf(v.w);
  a.d[seg][j] = o;
}

// ---------------- bf16 NT GEMM body: Y = X * Wt^T + bias ------------------
// (R6-verified) 128x128 tile, BK=64, 4 waves, gl16 staging + XOR swizzle.
// MODE: 1 = f32 out (nontemporal); 2 = bf16 + per-head LN;
//       3 = bf16 + per-head LN + ATTN_SCALE;
//       4 = bf16 TRANSPOSED per-head out -> Y[bh][hd][kv]  (fused V-transpose)
template <int MODE>
DEVFN void gemm_body(const u16* __restrict__ X, const u16* __restrict__ Wt,
                     const float* __restrict__ bias,
                     const float* __restrict__ lng, const float* __restrict__ lnb,
                     void* __restrict__ Y, int M, int N, int K,
                     int m0, int n0, u16* Sh, float (*Sm)[128], float (*Sq)[128]) {
  u16* As = Sh;
  u16* Bs = Sh + 128 * 64;
  const int tid = threadIdx.x;
  const int w = tid >> 6, l = tid & 63;
  const int wr = w >> 1, wc = w & 1;
  const int lr = l & 15, lk = (l >> 4) * 8;
  const int rsw = (l & 7) << 3;               // read-side swizzle (u16 units)
  const int srow = l >> 3;
  const int scb = (l & 7) * 16;
  f32x4 acc[4][4] = {};

  for (int k0 = 0; k0 < K; k0 += 64) {
#pragma unroll
    for (int i = 0; i < 4; ++i) {
      int rbase = w * 32 + i * 8;
      int row = rbase + srow;
      int cb = scb ^ ((row & 7) << 4);        // inverse-swizzled source col (bytes)
      gl16((const char*)&X[(size_t)(m0 + row) * K + k0] + cb, &As[rbase * 64]);
      gl16((const char*)&Wt[(size_t)(n0 + row) * K + k0] + cb, &Bs[rbase * 64]);
    }
    __syncthreads();
    bf8 af[4][2], bfr[4][2];
#pragma unroll
    for (int mi = 0; mi < 4; ++mi)
#pragma unroll
      for (int kk = 0; kk < 2; ++kk)
        af[mi][kk] = *(const bf8*)&As[(wr * 64 + mi * 16 + lr) * 64 + ((kk * 32 + lk) ^ rsw)];
#pragma unroll
    for (int ni = 0; ni < 4; ++ni)
#pragma unroll
      for (int kk = 0; kk < 2; ++kk)
        bfr[ni][kk] = *(const bf8*)&Bs[(wc * 64 + ni * 16 + lr) * 64 + ((kk * 32 + lk) ^ rsw)];
#pragma unroll
    for (int kk = 0; kk < 2; ++kk)
#pragma unroll
      for (int mi = 0; mi < 4; ++mi)
#pragma unroll
        for (int ni = 0; ni < 4; ++ni)
          acc[mi][ni] = mfma16(af[mi][kk], bfr[ni][kk], acc[mi][ni]);
    __syncthreads();
  }
  const int lrg = (l >> 4) * 4;

  // bias (pre-LN, matching reference: LN(x@W^T + b))
  float bv[4];
#pragma unroll
  for (int ni = 0; ni < 4; ++ni) bv[ni] = bias[n0 + wc * 64 + ni * 16 + lr];
#pragma unroll
  for (int mi = 0; mi < 4; ++mi)
#pragma unroll
    for (int ni = 0; ni < 4; ++ni)
#pragma unroll
      for (int r = 0; r < 4; ++r) acc[mi][ni][r] += bv[ni];

  if constexpr (MODE == 2 || MODE == 3) {
#pragma unroll
    for (int mi = 0; mi < 4; ++mi) {
#pragma unroll
      for (int r = 0; r < 4; ++r) {
        float ps = 0.f, pq = 0.f;
#pragma unroll
        for (int ni = 0; ni < 4; ++ni) {
          float v = acc[mi][ni][r];
          ps += v; pq += v * v;
        }
#pragma unroll
        for (int m = 1; m < 16; m <<= 1) {
          ps += __shfl_xor(ps, m);
          pq += __shfl_xor(pq, m);
        }
        if (lr == 0) {
          int rl = wr * 64 + mi * 16 + lrg + r;
          Sm[wc][rl] = ps; Sq[wc][rl] = pq;
        }
      }
    }
    __syncthreads();
    float gv[4], bbv[4];
#pragma unroll
    for (int ni = 0; ni < 4; ++ni) {
      int c = wc * 64 + ni * 16 + lr;          // col within head (n-tile aligned)
      gv[ni] = lng[c]; bbv[ni] = lnb[c];
    }
#pragma unroll
    for (int mi = 0; mi < 4; ++mi)
#pragma unroll
      for (int r = 0; r < 4; ++r) {
        int rl = wr * 64 + mi * 16 + lrg + r;
        float mean = (Sm[0][rl] + Sm[1][rl]) * (1.f / 128.f);
        float var  = (Sq[0][rl] + Sq[1][rl]) * (1.f / 128.f) - mean * mean;
        float rs = rsqrtf(var + LN_EPS);
#pragma unroll
        for (int ni = 0; ni < 4; ++ni) {
          float o = (acc[mi][ni][r] - mean) * rs * gv[ni] + bbv[ni];
          if (MODE == 3) o *= ATTN_SCALE;
          acc[mi][ni][r] = o;
        }
      }
  }

  if constexpr (MODE == 4) {
    u16* T = Sh;                               // 128*128 u16 = 32 KB
#pragma unroll
    for (int mi = 0; mi < 4; ++mi)
#pragma unroll
      for (int ni = 0; ni < 4; ++ni)
#pragma unroll
        for (int r = 0; r < 4; ++r) {
          int mrow = wr * 64 + mi * 16 + lrg + r;
          int ncol = wc * 64 + ni * 16 + lr;
          T[mrow * 128 + (ncol ^ ((mrow & 7) << 3))] = f2bf(acc[mi][ni][r]);
        }
    __syncthreads();
    int hd = tid >> 1, half = tid & 1;
    int bq = m0 >> 12;                          // m = b*LKV + kv, LKV=4096
    int kvb = (m0 & (LKV - 1)) + half * 64;
    int hh = n0 >> 7;                           // n-tile == head
    u16* vout = (u16*)Y + ((size_t)(bq * NH + hh) * HDm + hd) * LKV + kvb;
#pragma unroll
    for (int j8 = 0; j8 < 8; ++j8) {
      u16 tmp[8] __attribute__((aligned(16)));
#pragma unroll
      for (int j = 0; j < 8; ++j) {
        int kv = half * 64 + j8 * 8 + j;
        tmp[j] = T[kv * 128 + (hd ^ ((kv & 7) << 3))];
      }
      *(int4*)&vout[j8 * 8] = *(const int4*)tmp;
    }
    return;
  }

#pragma unroll
  for (int ni = 0; ni < 4; ++ni) {
    int n = n0 + wc * 64 + ni * 16 + lr;
#pragma unroll
    for (int mi = 0; mi < 4; ++mi) {
      int mb = m0 + wr * 64 + mi * 16 + lrg;
#pragma unroll
      for (int r = 0; r < 4; ++r) {
        float v = acc[mi][ni][r];
        if constexpr (MODE == 1)
          __builtin_nontemporal_store(v, &((float*)Y)[(size_t)(mb + r) * N + n]);
        else
          ((u16*)Y)[(size_t)(mb + r) * N + n] = f2bf(v);
      }
    }
  }
}

// ---------------- merged Q/K/V projection launch ---------------------------
// 2560 blocks: [0,512) Q (MODE3, LN+scale), [512,1536) K (MODE2, LN),
// [1536,2560) V (MODE4, transposed out). One launch -> no inter-GEMM drains,
// segment tails overlap the next segment's head.
__global__ __launch_bounds__(256) void k_qkv(const u16* __restrict__ hsb,
                                             const u16* __restrict__ casb,
                                             const u16* __restrict__ qwb,
                                             const u16* __restrict__ kwb,
                                             const u16* __restrict__ vwb,
                                             const float* __restrict__ q_b,
                                             const float* __restrict__ k_b,
                                             const float* __restrict__ v_b,
                                             const float* __restrict__ qn_g,
                                             const float* __restrict__ qn_b,
                                             const float* __restrict__ kn_g,
                                             const float* __restrict__ kn_b,
                                             u16* __restrict__ Qp,
                                             u16* __restrict__ Kp,
                                             u16* __restrict__ Vtp) {
  __shared__ __align__(16) u16 Sh[2 * 128 * 64];
  __shared__ float Sm[2][128], Sq[2][128];
  const int bx = blockIdx.x;
  if (bx < 512) {                 // Q: M=4096 -> 32 m-blocks x 16 n-blocks
    int m0 = (bx & 31) << 7, n0 = (bx >> 5) << 7;
    gemm_body<3>(hsb, qwb, q_b, qn_g, qn_b, Qp, BB * LQ, DD, DD, m0, n0, Sh, Sm, Sq);
  } else if (bx < 1536) {         // K: M=8192 -> 64 x 16
    int i = bx - 512;
    int m0 = (i & 63) << 7, n0 = (i >> 6) << 7;
    gemm_body<2>(casb, kwb, k_b, kn_g, kn_b, Kp, BB * LKV, DD, DD, m0, n0, Sh, Sm, Sq);
  } else {                        // V: M=8192 -> 64 x 16, transposed out
    int i = bx - 1536;
    int m0 = (i & 63) << 7, n0 = (i >> 6) << 7;
    gemm_body<4>(casb, vwb, v_b, nullptr, nullptr, Vtp, BB * LKV, DD, DD, m0, n0, Sh, Sm, Sq);
  }
}

// ---------------- O projection (separate: depends on attn) -----------------
template <int MODE>
__global__ __launch_bounds__(256) void k_gemm_nt(const u16* __restrict__ X,
                                                 const u16* __restrict__ Wt,
                                                 const float* __restrict__ bias,
                                                 const float* __restrict__ lng,
                                                 const float* __restrict__ lnb,
                                                 void* __restrict__ Y,
                                                 int M, int N, int K) {
  __shared__ __align__(16) u16 Sh[2 * 128 * 64];
  __shared__ float Sm[2][128], Sq[2][128];
  gemm_body<MODE>(X, Wt, bias, lng, lnb, Y, M, N, K,
                  blockIdx.x * 128, blockIdx.y * 128, Sh, Sm, Sq);
}

// ---------------- fused attention (R10-verified, 745.7 us config) ----------
// 512 threads / 8 waves, q-tile 128. Pass A: kv-tile 128 (Ks+Vs unioned as two
// 32KB dbuf regions), lane-local row sums. Pass B: kv-tile 64, dbuf, P in
// registers (lane lr owns q-row lr), pf assembled via shfl; Wout written as
// f32x4 nontemporal. One barrier + counted vmcnt per iter.
__global__ __launch_bounds__(512, 4) void k_attn(const u16* __restrict__ Qp,
                                                 const u16* __restrict__ Kp,
                                                 const u16* __restrict__ Vt,
                                                 float* __restrict__ Wout,
                                                 u16* __restrict__ AO) {
  const int g = blockIdx.x;                 // 512 blocks, 8 XCDs, 64 each
  const int work = (g & 7) * 64 + (g >> 3);
  const int bh = work >> 4;
  const int b = bh >> 4, h = bh & 15;
  const int q0 = (work & 15) * 128;
  const int tid = threadIdx.x, w = tid >> 6, l = tid & 63;
  const int lr = l & 15, lk = (l >> 4) * 8;
  const int gq = l >> 4;                    // lane group 0..3 (kv sub-quad)
  const int rsw = (l & 7) << 3;             // read swizzle, u16 units
  __shared__ __align__(16) u16 Ks[2][64 * 128];
  __shared__ __align__(16) u16 Vs[2][128 * 64];

  // hoist Q fragments (B-frag for swapped mfma: col = lr, 8 k-els at kc*32+lk)
  bf8 qf[4];
  {
    const u16* qb = &Qp[((size_t)b * LQ + q0 + w * 16 + lr) * DD + h * HDm];
#pragma unroll
    for (int kc = 0; kc < 4; ++kc) qf[kc] = *(const bf8*)(qb + kc * 32 + lk);
  }
  const u16* Kb = Kp + (size_t)b * LKV * DD + h * HDm;   // row stride DD
  const u16* Vb = Vt + (size_t)bh * HDm * LKV;           // row (hd) stride LKV

  // ---- staging helpers
  auto stageK128 = [&](u16* buf, int kv0) {   // 128 rows x 256 B into 32KB region
#pragma unroll
    for (int i = 0; i < 4; ++i) {
      int rbase = i * 32 + w * 4;
      int row = rbase + (l >> 4);
      int cb = ((l & 15) * 16) ^ ((row & 7) << 4);
      gl16((const char*)(Kb + (size_t)(kv0 + row) * DD) + cb, &buf[rbase * 128]);
    }
  };
  auto stageK = [&](int buf, int kv0) {       // 64 rows x 256 B
#pragma unroll
    for (int i = 0; i < 2; ++i) {
      int rbase = i * 32 + w * 4;
      int row = rbase + (l >> 4);
      int cb = ((l & 15) * 16) ^ ((row & 7) << 4);
      gl16((const char*)(Kb + (size_t)(kv0 + row) * DD) + cb, &Ks[buf][rbase * 128]);
    }
  };
  auto stageV = [&](int buf, int kv0) {       // 128 rows x 128 B
#pragma unroll
    for (int i = 0; i < 2; ++i) {
      int rbase = i * 64 + w * 8;
      int row = rbase + (l >> 3);
      int cb = ((l & 7) * 16) ^ ((row & 7) << 4);
      gl16((const char*)(Vb + (size_t)row * LKV + kv0) + cb, &Vs[buf][rbase * 64]);
    }
  };

  // ================= pass A: lane-local row sums, kv-tile 128 ==============
  u16* bufA0 = &Ks[0][0];                    // 32KB region = 128 rows x 128 u16
  u16* bufA1 = &Vs[0][0];
  float lsum = 0.f;
  stageK128(bufA0, 0);
  asm volatile("s_waitcnt vmcnt(0)" ::: "memory");
  barrier_hard();
  for (int t = 0; t < 32; ++t) {
    const u16* kb = (t & 1) ? bufA1 : bufA0;
    if (t < 31) stageK128((t & 1) ? bufA0 : bufA1, (t + 1) * 128);
    f32x4 s8[8];
    __builtin_amdgcn_s_setprio(1);
#pragma unroll
    for (int ni = 0; ni < 8; ++ni) {
      s8[ni] = f32x4{0.f, 0.f, 0.f, 0.f};
#pragma unroll
      for (int kc = 0; kc < 4; ++kc) {
        bf8 kf = *(const bf8*)&kb[(ni * 16 + lr) * 128 + ((kc * 32 + lk) ^ rsw)];
        s8[ni] = mfma16(kf, qf[kc], s8[ni]);
      }
    }
    __builtin_amdgcn_s_setprio(0);
#pragma unroll
    for (int ni = 0; ni < 8; ++ni)
#pragma unroll
      for (int r = 0; r < 4; ++r)
        lsum += exp2f(fmaf(s8[ni][r], LOG2E, -SHIFT2));
    asm volatile("s_waitcnt vmcnt(0)" ::: "memory");  // next tile staged
    barrier_hard();
  }
  // lane lr holds partials of q-row lr; combine the 4 lane-groups
  lsum += __shfl_xor(lsum, 16);
  lsum += __shfl_xor(lsum, 32);
  const float cr = -(SHIFT2 + __log2f(lsum));   // exp2(s*log2e + cr) = p/sum

  // ================= pass B: weights + PV, kv-tile 64 =======================
  f32x4 oacc[8] = {};
  float* wq = Wout + ((size_t)bh * LQ + q0 + w * 16 + lr) * LKV;
  const int srcA = lr + ((gq & 1) << 5);
  const int srcB = srcA + 16;
  const bool hi = (gq >> 1) != 0;

  stageK(0, 0); stageV(0, 0);
  asm volatile("s_waitcnt vmcnt(0)" ::: "memory");
  barrier_hard();
  for (int t = 0; t < 64; ++t) {
    const int cur = t & 1;
    const int kv0 = t * 64;
    if (t < 63) { stageK(cur ^ 1, kv0 + 64); stageV(cur ^ 1, kv0 + 64); }
    // QK swapped: s[ni] rows = kv (ni*16 + 4*gq + r), col = q-row lr
    f32x4 s[4];
    __builtin_amdgcn_s_setprio(1);
#pragma unroll
    for (int ni = 0; ni < 4; ++ni) {
      s[ni] = f32x4{0.f, 0.f, 0.f, 0.f};
#pragma unroll
      for (int kc = 0; kc < 4; ++kc) {
        bf8 kf = *(const bf8*)&Ks[cur][(ni * 16 + lr) * 128 + ((kc * 32 + lk) ^ rsw)];
        s[ni] = mfma16(kf, qf[kc], s[ni]);
      }
    }
    __builtin_amdgcn_s_setprio(0);
    // normalized p: 4 contiguous kv per lane -> f32x4 nontemporal stores
    unsigned pk2[4][2];
#pragma unroll
    for (int ni = 0; ni < 4; ++ni) {
      float p0 = exp2f(fmaf(s[ni][0], LOG2E, cr));
      float p1 = exp2f(fmaf(s[ni][1], LOG2E, cr));
      float p2 = exp2f(fmaf(s[ni][2], LOG2E, cr));
      float p3 = exp2f(fmaf(s[ni][3], LOG2E, cr));
      f32x4 pv4 = {p0, p1, p2, p3};
      __builtin_nontemporal_store(pv4, (f32x4*)(wq + kv0 + ni * 16 + 4 * gq));
      pk2[ni][0] = (unsigned)f2bf(p0) | ((unsigned)f2bf(p1) << 16);
      pk2[ni][1] = (unsigned)f2bf(p2) | ((unsigned)f2bf(p3) << 16);
    }
    // assemble pf (A-frag of PV: q-row lr, 8 kv at kk*32+8*gq) via shfl + PV
#pragma unroll
    for (int kk = 0; kk < 2; ++kk) {
      unsigned xa0 = __shfl(pk2[2 * kk][0], srcA), xa1 = __shfl(pk2[2 * kk][1], srcA);
      unsigned ya0 = __shfl(pk2[2 * kk + 1][0], srcA), ya1 = __shfl(pk2[2 * kk + 1][1], srcA);
      unsigned xb0 = __shfl(pk2[2 * kk][0], srcB), xb1 = __shfl(pk2[2 * kk][1], srcB);
      unsigned yb0 = __shfl(pk2[2 * kk + 1][0], srcB), yb1 = __shfl(pk2[2 * kk + 1][1], srcB);
      u32x4 pf32 = { hi ? ya0 : xa0, hi ? ya1 : xa1, hi ? yb0 : xb0, hi ? yb1 : xb1 };
      bf8 pf = __builtin_bit_cast(bf8, pf32);
      __builtin_amdgcn_s_setprio(1);
#pragma unroll
      for (int c = 0; c < 8; ++c) {
        bf8 vf = *(const bf8*)&Vs[cur][(c * 16 + lr) * 64 + ((kk * 32 + lk) ^ rsw)];
        oacc[c] = mfma16(pf, vf, oacc[c]);
      }
      __builtin_amdgcn_s_setprio(0);
    }
    // drain the 4 prefetch loads; leave the 4 newest (stores) in flight
    asm volatile("s_waitcnt vmcnt(4)" ::: "memory");
    barrier_hard();
  }

  // epilogue: AO [B, Lq, D] bf16 (oacc rows q = 4*gq + r, cols hd = c*16+lr)
#pragma unroll
  for (int c = 0; c < 8; ++c)
#pragma unroll
    for (int r = 0; r < 4; ++r)
      AO[((size_t)b * LQ + q0 + w * 16 + 4 * gq + r) * DD + h * HDm + c * 16 + lr] =
          f2bf(oacc[c][r]);
}

// ---------------------------------------------------------------------------
extern "C" void kernel_launch(void* const* d_in, const int* in_sizes, int n_in,
                              void* d_out, int out_size, void* d_ws, size_t ws_size,
                              hipStream_t stream) {
  const float* hs   = (const float*)d_in[0];
  const float* cas  = (const float*)d_in[1];
  const float* q_w  = (const float*)d_in[2];
  const float* q_b  = (const float*)d_in[3];
  const float* k_w  = (const float*)d_in[4];
  const float* k_b  = (const float*)d_in[5];
  const float* v_w  = (const float*)d_in[6];
  const float* v_b  = (const float*)d_in[7];
  const float* o_w  = (const float*)d_in[8];
  const float* o_b  = (const float*)d_in[9];
  const float* qn_g = (const float*)d_in[10];
  const float* qn_b = (const float*)d_in[11];
  const float* kn_g = (const float*)d_in[12];
  const float* kn_b = (const float*)d_in[13];

  float* out_attn = (float*)d_out;
  float* out_w    = out_attn + (size_t)BB * LQ * DD;

  constexpr size_t SZ_Q  = (size_t)BB * LQ * DD * 2;
  constexpr size_t SZ_KV = (size_t)BB * LKV * DD * 2;
  constexpr size_t SZ_W  = (size_t)DD * DD * 2;
  char* p = (char*)d_ws;
  u16* hsb  = (u16*)p;              p += SZ_Q;
  u16* casb = (u16*)p;              p += SZ_KV;
  u16* qwb  = (u16*)p;              p += SZ_W;
  u16* kwb  = (u16*)p;              p += SZ_W;
  u16* vwb  = (u16*)p;              p += SZ_W;
  u16* owb  = (u16*)p;              p += SZ_W;
  u16* Qp   = (u16*)p;              p += SZ_Q;
  u16* Kp   = (u16*)p;              p += SZ_KV;
  u16* Vtp  = (u16*)p;              p += SZ_KV;
  u16* AO   = (u16*)p;              p += SZ_Q;

  // 1) all f32->bf16 conversions in one launch
  constexpr unsigned HS4 = BB * LQ * DD / 4;
  constexpr unsigned CAS4 = BB * LKV * DD / 4;
  constexpr unsigned W4 = DD * DD / 4;
  C6 a;
  a.s[0] = (const float4*)hs;  a.d[0] = (ushort4*)hsb;
  a.s[1] = (const float4*)cas; a.d[1] = (ushort4*)casb;
  a.s[2] = (const float4*)q_w; a.d[2] = (ushort4*)qwb;
  a.s[3] = (const float4*)k_w; a.d[3] = (ushort4*)kwb;
  a.s[4] = (const float4*)v_w; a.d[4] = (ushort4*)vwb;
  a.s[5] = (const float4*)o_w; a.d[5] = (ushort4*)owb;
  a.off[0] = 0;
  a.off[1] = HS4;
  a.off[2] = HS4 + CAS4;
  a.off[3] = HS4 + CAS4 + W4;
  a.off[4] = HS4 + CAS4 + 2 * W4;
  a.off[5] = HS4 + CAS4 + 3 * W4;
  a.off[6] = HS4 + CAS4 + 4 * W4;
  k_cvt6<<<dim3((a.off[6] + 255) / 256), dim3(256), 0, stream>>>(a);

  // 2) merged Q/K/V projections (one launch, 2560 blocks)
  k_qkv<<<dim3(2560), dim3(256), 0, stream>>>(
      hsb, casb, qwb, kwb, vwb, q_b, k_b, v_b,
      qn_g, qn_b, kn_g, kn_b, Qp, Kp, Vtp);

  // 3) fused attention (pass A sums + pass B weights/PV)
  k_attn<<<dim3(LQ / 128 * BB * NH), dim3(512), 0, stream>>>(Qp, Kp, Vtp, out_w, AO);

  // 4) O projection -> fp32 into d_out
  k_gemm_nt<1><<<dim3(BB * LQ / 128, DD / 128), dim3(256), 0, stream>>>(
      AO, owb, o_b, nullptr, nullptr, out_attn, BB * LQ, DD, DD);
}

// Round 13
// 737.794 us; speedup vs baseline: 1.0252x; 1.0070x over previous
//
#include <hip/hip_runtime.h>
#include <cstdint>
#include <cstddef>

using u16 = unsigned short;
using f32x4 = __attribute__((ext_vector_type(4))) float;
using bf8   = __attribute__((ext_vector_type(8))) short;   // 8 bf16 in 4 VGPRs
using u32x4 = __attribute__((ext_vector_type(4))) unsigned;

#define DEVFN __device__ __forceinline__

constexpr int BB  = 2;
constexpr int LQ  = 2048;
constexpr int LKV = 4096;
constexpr int DD  = 2048;
constexpr int NH  = 16;
constexpr int HDm = 128;
constexpr float ATTN_SCALE = 0.08838834764831845f;  // 128^-0.5
constexpr float LN_EPS = 1e-6f;
// softmax fixed shift: LN guarantees |s| <= ||q*scale||*||k|| = 1*sqrt(128) ~ 11.4
constexpr float LOG2E  = 1.4426950408889634f;
constexpr float SHIFT2 = 17.312340490667562f;       // 12.0 * log2(e)

DEVFN u16 f2bf(float f) {
  unsigned u = __builtin_bit_cast(unsigned, f);
  u += 0x7fffu + ((u >> 16) & 1u);          // RNE
  return (u16)(u >> 16);
}
DEVFN float bf2f(u16 h) { return __builtin_bit_cast(float, (unsigned)h << 16); }
DEVFN f32x4 mfma16(bf8 a, bf8 b, f32x4 c) {
  return __builtin_amdgcn_mfma_f32_16x16x32_bf16(a, b, c, 0, 0, 0);
}
// async global->LDS, 16B/lane, lane i lands at lds + i*16 (wave-uniform lds base)
DEVFN void gl16(const void* g, void* l) {
  __builtin_amdgcn_global_load_lds(
      (const __attribute__((address_space(1))) void*)g,
      (__attribute__((address_space(3))) void*)l, 16, 0, 0);
}
DEVFN void barrier_hard() {                 // raw barrier + scheduler fence
  __builtin_amdgcn_s_barrier();
  __builtin_amdgcn_sched_barrier(0);
}

// ---------------- fused f32 -> bf16 convert, ALL segments in one launch ----
struct C6 {
  const float4* s[6];
  ushort4* d[6];
  unsigned off[7];                          // prefix sums in float4 units
};
__global__ __launch_bounds__(256) void k_cvt6(C6 a) {
  unsigned gi = blockIdx.x * 256 + threadIdx.x;
  if (gi >= a.off[6]) return;
  int seg = 0;
#pragma unroll
  for (int i = 1; i < 6; ++i) seg += (gi >= a.off[i]);
  unsigned j = gi - a.off[seg];
  float4 v = a.s[seg][j];
  ushort4 o;
  o.x = f2bf(v.x); o.y = f2bf(v.y); o.z = f2bf(v.z); o.w = f2bf(v.w);
  a.d[seg][j] = o;
}

// ---------------- bf16 NT GEMM body: Y = X * Wt^T + bias ------------------
// (R6-verified) 128x128 tile, BK=64, 4 waves, gl16 staging + XOR swizzle.
// MODE: 1 = f32 out (nontemporal); 2 = bf16 + per-head LN;
//       3 = bf16 + per-head LN + ATTN_SCALE;
//       4 = bf16 TRANSPOSED per-head out -> Y[bh][hd][kv]  (fused V-transpose)
template <int MODE>
DEVFN void gemm_body(const u16* __restrict__ X, const u16* __restrict__ Wt,
                     const float* __restrict__ bias,
                     const float* __restrict__ lng, const float* __restrict__ lnb,
                     void* __restrict__ Y, int M, int N, int K,
                     int m0, int n0, u16* Sh, float (*Sm)[128], float (*Sq)[128]) {
  u16* As = Sh;
  u16* Bs = Sh + 128 * 64;
  const int tid = threadIdx.x;
  const int w = tid >> 6, l = tid & 63;
  const int wr = w >> 1, wc = w & 1;
  const int lr = l & 15, lk = (l >> 4) * 8;
  const int rsw = (l & 7) << 3;               // read-side swizzle (u16 units)
  const int srow = l >> 3;
  const int scb = (l & 7) * 16;
  f32x4 acc[4][4] = {};

  for (int k0 = 0; k0 < K; k0 += 64) {
#pragma unroll
    for (int i = 0; i < 4; ++i) {
      int rbase = w * 32 + i * 8;
      int row = rbase + srow;
      int cb = scb ^ ((row & 7) << 4);        // inverse-swizzled source col (bytes)
      gl16((const char*)&X[(size_t)(m0 + row) * K + k0] + cb, &As[rbase * 64]);
      gl16((const char*)&Wt[(size_t)(n0 + row) * K + k0] + cb, &Bs[rbase * 64]);
    }
    __syncthreads();
    bf8 af[4][2], bfr[4][2];
#pragma unroll
    for (int mi = 0; mi < 4; ++mi)
#pragma unroll
      for (int kk = 0; kk < 2; ++kk)
        af[mi][kk] = *(const bf8*)&As[(wr * 64 + mi * 16 + lr) * 64 + ((kk * 32 + lk) ^ rsw)];
#pragma unroll
    for (int ni = 0; ni < 4; ++ni)
#pragma unroll
      for (int kk = 0; kk < 2; ++kk)
        bfr[ni][kk] = *(const bf8*)&Bs[(wc * 64 + ni * 16 + lr) * 64 + ((kk * 32 + lk) ^ rsw)];
#pragma unroll
    for (int kk = 0; kk < 2; ++kk)
#pragma unroll
      for (int mi = 0; mi < 4; ++mi)
#pragma unroll
        for (int ni = 0; ni < 4; ++ni)
          acc[mi][ni] = mfma16(af[mi][kk], bfr[ni][kk], acc[mi][ni]);
    __syncthreads();
  }
  const int lrg = (l >> 4) * 4;

  // bias (pre-LN, matching reference: LN(x@W^T + b))
  float bv[4];
#pragma unroll
  for (int ni = 0; ni < 4; ++ni) bv[ni] = bias[n0 + wc * 64 + ni * 16 + lr];
#pragma unroll
  for (int mi = 0; mi < 4; ++mi)
#pragma unroll
    for (int ni = 0; ni < 4; ++ni)
#pragma unroll
      for (int r = 0; r < 4; ++r) acc[mi][ni][r] += bv[ni];

  if constexpr (MODE == 2 || MODE == 3) {
#pragma unroll
    for (int mi = 0; mi < 4; ++mi) {
#pragma unroll
      for (int r = 0; r < 4; ++r) {
        float ps = 0.f, pq = 0.f;
#pragma unroll
        for (int ni = 0; ni < 4; ++ni) {
          float v = acc[mi][ni][r];
          ps += v; pq += v * v;
        }
#pragma unroll
        for (int m = 1; m < 16; m <<= 1) {
          ps += __shfl_xor(ps, m);
          pq += __shfl_xor(pq, m);
        }
        if (lr == 0) {
          int rl = wr * 64 + mi * 16 + lrg + r;
          Sm[wc][rl] = ps; Sq[wc][rl] = pq;
        }
      }
    }
    __syncthreads();
    float gv[4], bbv[4];
#pragma unroll
    for (int ni = 0; ni < 4; ++ni) {
      int c = wc * 64 + ni * 16 + lr;          // col within head (n-tile aligned)
      gv[ni] = lng[c]; bbv[ni] = lnb[c];
    }
#pragma unroll
    for (int mi = 0; mi < 4; ++mi)
#pragma unroll
      for (int r = 0; r < 4; ++r) {
        int rl = wr * 64 + mi * 16 + lrg + r;
        float mean = (Sm[0][rl] + Sm[1][rl]) * (1.f / 128.f);
        float var  = (Sq[0][rl] + Sq[1][rl]) * (1.f / 128.f) - mean * mean;
        float rs = rsqrtf(var + LN_EPS);
#pragma unroll
        for (int ni = 0; ni < 4; ++ni) {
          float o = (acc[mi][ni][r] - mean) * rs * gv[ni] + bbv[ni];
          if (MODE == 3) o *= ATTN_SCALE;
          acc[mi][ni][r] = o;
        }
      }
  }

  if constexpr (MODE == 4) {
    u16* T = Sh;                               // 128*128 u16 = 32 KB
#pragma unroll
    for (int mi = 0; mi < 4; ++mi)
#pragma unroll
      for (int ni = 0; ni < 4; ++ni)
#pragma unroll
        for (int r = 0; r < 4; ++r) {
          int mrow = wr * 64 + mi * 16 + lrg + r;
          int ncol = wc * 64 + ni * 16 + lr;
          T[mrow * 128 + (ncol ^ ((mrow & 7) << 3))] = f2bf(acc[mi][ni][r]);
        }
    __syncthreads();
    int hd = tid >> 1, half = tid & 1;
    int bq = m0 >> 12;                          // m = b*LKV + kv, LKV=4096
    int kvb = (m0 & (LKV - 1)) + half * 64;
    int hh = n0 >> 7;                           // n-tile == head
    u16* vout = (u16*)Y + ((size_t)(bq * NH + hh) * HDm + hd) * LKV + kvb;
#pragma unroll
    for (int j8 = 0; j8 < 8; ++j8) {
      u16 tmp[8] __attribute__((aligned(16)));
#pragma unroll
      for (int j = 0; j < 8; ++j) {
        int kv = half * 64 + j8 * 8 + j;
        tmp[j] = T[kv * 128 + (hd ^ ((kv & 7) << 3))];
      }
      *(int4*)&vout[j8 * 8] = *(const int4*)tmp;
    }
    return;
  }

#pragma unroll
  for (int ni = 0; ni < 4; ++ni) {
    int n = n0 + wc * 64 + ni * 16 + lr;
#pragma unroll
    for (int mi = 0; mi < 4; ++mi) {
      int mb = m0 + wr * 64 + mi * 16 + lrg;
#pragma unroll
      for (int r = 0; r < 4; ++r) {
        float v = acc[mi][ni][r];
        if constexpr (MODE == 1)
          __builtin_nontemporal_store(v, &((float*)Y)[(size_t)(mb + r) * N + n]);
        else
          ((u16*)Y)[(size_t)(mb + r) * N + n] = f2bf(v);
      }
    }
  }
}

// ---------------- merged Q/K/V projection launch ---------------------------
__global__ __launch_bounds__(256) void k_qkv(const u16* __restrict__ hsb,
                                             const u16* __restrict__ casb,
                                             const u16* __restrict__ qwb,
                                             const u16* __restrict__ kwb,
                                             const u16* __restrict__ vwb,
                                             const float* __restrict__ q_b,
                                             const float* __restrict__ k_b,
                                             const float* __restrict__ v_b,
                                             const float* __restrict__ qn_g,
                                             const float* __restrict__ qn_b,
                                             const float* __restrict__ kn_g,
                                             const float* __restrict__ kn_b,
                                             u16* __restrict__ Qp,
                                             u16* __restrict__ Kp,
                                             u16* __restrict__ Vtp) {
  __shared__ __align__(16) u16 Sh[2 * 128 * 64];
  __shared__ float Sm[2][128], Sq[2][128];
  const int bx = blockIdx.x;
  if (bx < 512) {                 // Q: M=4096 -> 32 m-blocks x 16 n-blocks
    int m0 = (bx & 31) << 7, n0 = (bx >> 5) << 7;
    gemm_body<3>(hsb, qwb, q_b, qn_g, qn_b, Qp, BB * LQ, DD, DD, m0, n0, Sh, Sm, Sq);
  } else if (bx < 1536) {         // K: M=8192 -> 64 x 16
    int i = bx - 512;
    int m0 = (i & 63) << 7, n0 = (i >> 6) << 7;
    gemm_body<2>(casb, kwb, k_b, kn_g, kn_b, Kp, BB * LKV, DD, DD, m0, n0, Sh, Sm, Sq);
  } else {                        // V: M=8192 -> 64 x 16, transposed out
    int i = bx - 1536;
    int m0 = (i & 63) << 7, n0 = (i >> 6) << 7;
    gemm_body<4>(casb, vwb, v_b, nullptr, nullptr, Vtp, BB * LKV, DD, DD, m0, n0, Sh, Sm, Sq);
  }
}

// ---------------- O projection (separate: depends on attn) -----------------
template <int MODE>
__global__ __launch_bounds__(256) void k_gemm_nt(const u16* __restrict__ X,
                                                 const u16* __restrict__ Wt,
                                                 const float* __restrict__ bias,
                                                 const float* __restrict__ lng,
                                                 const float* __restrict__ lnb,
                                                 void* __restrict__ Y,
                                                 int M, int N, int K) {
  __shared__ __align__(16) u16 Sh[2 * 128 * 64];
  __shared__ float Sm[2][128], Sq[2][128];
  gemm_body<MODE>(X, Wt, bias, lng, lnb, Y, M, N, K,
                  blockIdx.x * 128, blockIdx.y * 128, Sh, Sm, Sq);
}

// ---------------- fused attention ------------------------------------------
// 512 threads / 8 waves, q-tile 128. Pass A: PAIRED WAVES — waves (2j,2j+1)
// share 32 q-rows (dual qf); each wave covers HALF the kv rows of each
// 128-kv tile. LDS reads per wave halve (16 reads feed 32 MFMAs) — pass A
// was LDS-read-BW-bound 2x. Cross-pair sum combine via 1KB LDS. Pass B
// unchanged (R10 745.7us config): kv-tile 64 dbuf, P in registers, pf via
// shfl, Wout f32x4 nontemporal, counted vmcnt.
__global__ __launch_bounds__(512, 4) void k_attn(const u16* __restrict__ Qp,
                                                 const u16* __restrict__ Kp,
                                                 const u16* __restrict__ Vt,
                                                 float* __restrict__ Wout,
                                                 u16* __restrict__ AO) {
  const int g = blockIdx.x;                 // 512 blocks, 8 XCDs, 64 each
  const int work = (g & 7) * 64 + (g >> 3);
  const int bh = work >> 4;
  const int b = bh >> 4, h = bh & 15;
  const int q0 = (work & 15) * 128;
  const int tid = threadIdx.x, w = tid >> 6, l = tid & 63;
  const int lr = l & 15, lk = (l >> 4) * 8;
  const int gq = l >> 4;                    // lane group 0..3 (kv sub-quad)
  const int rsw = (l & 7) << 3;             // read swizzle, u16 units
  __shared__ __align__(16) u16 Ks[2][64 * 128];
  __shared__ __align__(16) u16 Vs[2][128 * 64];
  __shared__ float AsumS[8][2][16];         // pass-A cross-pair partial sums

  // Q fragments for the wave PAIR's 32 rows: qc=0,1 halves (B-frag: col=lr)
  bf8 qfA[2][4];
  {
    const int prow = (w >> 1) * 32;         // pair base q-row
#pragma unroll
    for (int qc = 0; qc < 2; ++qc) {
      const u16* qb = &Qp[((size_t)b * LQ + q0 + prow + qc * 16 + lr) * DD + h * HDm];
#pragma unroll
      for (int kc = 0; kc < 4; ++kc) qfA[qc][kc] = *(const bf8*)(qb + kc * 32 + lk);
    }
  }
  const u16* Kb = Kp + (size_t)b * LKV * DD + h * HDm;   // row stride DD
  const u16* Vb = Vt + (size_t)bh * HDm * LKV;           // row (hd) stride LKV

  // ---- staging helpers
  auto stageK128 = [&](u16* buf, int kv0) {   // 128 rows x 256 B into 32KB region
#pragma unroll
    for (int i = 0; i < 4; ++i) {
      int rbase = i * 32 + w * 4;
      int row = rbase + (l >> 4);
      int cb = ((l & 15) * 16) ^ ((row & 7) << 4);
      gl16((const char*)(Kb + (size_t)(kv0 + row) * DD) + cb, &buf[rbase * 128]);
    }
  };
  auto stageK = [&](int buf, int kv0) {       // 64 rows x 256 B
#pragma unroll
    for (int i = 0; i < 2; ++i) {
      int rbase = i * 32 + w * 4;
      int row = rbase + (l >> 4);
      int cb = ((l & 15) * 16) ^ ((row & 7) << 4);
      gl16((const char*)(Kb + (size_t)(kv0 + row) * DD) + cb, &Ks[buf][rbase * 128]);
    }
  };
  auto stageV = [&](int buf, int kv0) {       // 128 rows x 128 B
#pragma unroll
    for (int i = 0; i < 2; ++i) {
      int rbase = i * 64 + w * 8;
      int row = rbase + (l >> 3);
      int cb = ((l & 7) * 16) ^ ((row & 7) << 4);
      gl16((const char*)(Vb + (size_t)row * LKV + kv0) + cb, &Vs[buf][rbase * 64]);
    }
  };

  // ================= pass A: paired-wave row sums, kv-tile 128 ==============
  u16* bufA0 = &Ks[0][0];                    // 32KB region = 128 rows x 128 u16
  u16* bufA1 = &Vs[0][0];
  const int kvo = (w & 1) * 64;              // this wave's kv-half of the tile
  float lsum0 = 0.f, lsum1 = 0.f;
  stageK128(bufA0, 0);
  asm volatile("s_waitcnt vmcnt(0)" ::: "memory");
  barrier_hard();
  for (int t = 0; t < 32; ++t) {
    const u16* kb = (t & 1) ? bufA1 : bufA0;
    if (t < 31) stageK128((t & 1) ? bufA0 : bufA1, (t + 1) * 128);
#pragma unroll
    for (int ni = 0; ni < 4; ++ni) {
      f32x4 s0 = {0.f, 0.f, 0.f, 0.f}, s1 = {0.f, 0.f, 0.f, 0.f};
      __builtin_amdgcn_s_setprio(1);
#pragma unroll
      for (int kc = 0; kc < 4; ++kc) {
        bf8 kf = *(const bf8*)&kb[(kvo + ni * 16 + lr) * 128 + ((kc * 32 + lk) ^ rsw)];
        s0 = mfma16(kf, qfA[0][kc], s0);
        s1 = mfma16(kf, qfA[1][kc], s1);
      }
      __builtin_amdgcn_s_setprio(0);
#pragma unroll
      for (int r = 0; r < 4; ++r) {
        lsum0 += exp2f(fmaf(s0[r], LOG2E, -SHIFT2));
        lsum1 += exp2f(fmaf(s1[r], LOG2E, -SHIFT2));
      }
    }
    asm volatile("s_waitcnt vmcnt(0)" ::: "memory");  // next tile staged
    barrier_hard();
  }
  // combine lane groups (each lane class lr holds one q-row's partial)
  lsum0 += __shfl_xor(lsum0, 16); lsum0 += __shfl_xor(lsum0, 32);
  lsum1 += __shfl_xor(lsum1, 16); lsum1 += __shfl_xor(lsum1, 32);
  if (l < 16) { AsumS[w][0][l] = lsum0; AsumS[w][1][l] = lsum1; }
  __syncthreads();
  // wave w's pass-B rows = pair rows, half qc = w&1: total = mine + partner's
  float mine = (w & 1) ? lsum1 : lsum0;
  float tot = mine + AsumS[w ^ 1][w & 1][lr];
  const float cr = -(SHIFT2 + __log2f(tot));   // exp2(s*log2e + cr) = p/sum
  // pass-B qf = this wave's own 16 rows (static selection, rule #20)
  bf8 qf[4];
#pragma unroll
  for (int kc = 0; kc < 4; ++kc) qf[kc] = (w & 1) ? qfA[1][kc] : qfA[0][kc];

  // ================= pass B: weights + PV, kv-tile 64 =======================
  f32x4 oacc[8] = {};
  float* wq = Wout + ((size_t)bh * LQ + q0 + w * 16 + lr) * LKV;
  const int srcA = lr + ((gq & 1) << 5);
  const int srcB = srcA + 16;
  const bool hi = (gq >> 1) != 0;

  stageK(0, 0); stageV(0, 0);
  asm volatile("s_waitcnt vmcnt(0)" ::: "memory");
  barrier_hard();
  for (int t = 0; t < 64; ++t) {
    const int cur = t & 1;
    const int kv0 = t * 64;
    if (t < 63) { stageK(cur ^ 1, kv0 + 64); stageV(cur ^ 1, kv0 + 64); }
    // QK swapped: s[ni] rows = kv (ni*16 + 4*gq + r), col = q-row lr
    f32x4 s[4];
    __builtin_amdgcn_s_setprio(1);
#pragma unroll
    for (int ni = 0; ni < 4; ++ni) {
      s[ni] = f32x4{0.f, 0.f, 0.f, 0.f};
#pragma unroll
      for (int kc = 0; kc < 4; ++kc) {
        bf8 kf = *(const bf8*)&Ks[cur][(ni * 16 + lr) * 128 + ((kc * 32 + lk) ^ rsw)];
        s[ni] = mfma16(kf, qf[kc], s[ni]);
      }
    }
    __builtin_amdgcn_s_setprio(0);
    // normalized p: 4 contiguous kv per lane -> f32x4 nontemporal stores
    unsigned pk2[4][2];
#pragma unroll
    for (int ni = 0; ni < 4; ++ni) {
      float p0 = exp2f(fmaf(s[ni][0], LOG2E, cr));
      float p1 = exp2f(fmaf(s[ni][1], LOG2E, cr));
      float p2 = exp2f(fmaf(s[ni][2], LOG2E, cr));
      float p3 = exp2f(fmaf(s[ni][3], LOG2E, cr));
      f32x4 pv4 = {p0, p1, p2, p3};
      __builtin_nontemporal_store(pv4, (f32x4*)(wq + kv0 + ni * 16 + 4 * gq));
      pk2[ni][0] = (unsigned)f2bf(p0) | ((unsigned)f2bf(p1) << 16);
      pk2[ni][1] = (unsigned)f2bf(p2) | ((unsigned)f2bf(p3) << 16);
    }
    // assemble pf (A-frag of PV: q-row lr, 8 kv at kk*32+8*gq) via shfl + PV
#pragma unroll
    for (int kk = 0; kk < 2; ++kk) {
      unsigned xa0 = __shfl(pk2[2 * kk][0], srcA), xa1 = __shfl(pk2[2 * kk][1], srcA);
      unsigned ya0 = __shfl(pk2[2 * kk + 1][0], srcA), ya1 = __shfl(pk2[2 * kk + 1][1], srcA);
      unsigned xb0 = __shfl(pk2[2 * kk][0], srcB), xb1 = __shfl(pk2[2 * kk][1], srcB);
      unsigned yb0 = __shfl(pk2[2 * kk + 1][0], srcB), yb1 = __shfl(pk2[2 * kk + 1][1], srcB);
      u32x4 pf32 = { hi ? ya0 : xa0, hi ? ya1 : xa1, hi ? yb0 : xb0, hi ? yb1 : xb1 };
      bf8 pf = __builtin_bit_cast(bf8, pf32);
      __builtin_amdgcn_s_setprio(1);
#pragma unroll
      for (int c = 0; c < 8; ++c) {
        bf8 vf = *(const bf8*)&Vs[cur][(c * 16 + lr) * 64 + ((kk * 32 + lk) ^ rsw)];
        oacc[c] = mfma16(pf, vf, oacc[c]);
      }
      __builtin_amdgcn_s_setprio(0);
    }
    // drain the 4 prefetch loads; leave the 4 newest (stores) in flight
    asm volatile("s_waitcnt vmcnt(4)" ::: "memory");
    barrier_hard();
  }

  // epilogue: AO [B, Lq, D] bf16 (oacc rows q = 4*gq + r, cols hd = c*16+lr)
#pragma unroll
  for (int c = 0; c < 8; ++c)
#pragma unroll
    for (int r = 0; r < 4; ++r)
      AO[((size_t)b * LQ + q0 + w * 16 + 4 * gq + r) * DD + h * HDm + c * 16 + lr] =
          f2bf(oacc[c][r]);
}

// ---------------------------------------------------------------------------
extern "C" void kernel_launch(void* const* d_in, const int* in_sizes, int n_in,
                              void* d_out, int out_size, void* d_ws, size_t ws_size,
                              hipStream_t stream) {
  const float* hs   = (const float*)d_in[0];
  const float* cas  = (const float*)d_in[1];
  const float* q_w  = (const float*)d_in[2];
  const float* q_b  = (const float*)d_in[3];
  const float* k_w  = (const float*)d_in[4];
  const float* k_b  = (const float*)d_in[5];
  const float* v_w  = (const float*)d_in[6];
  const float* v_b  = (const float*)d_in[7];
  const float* o_w  = (const float*)d_in[8];
  const float* o_b  = (const float*)d_in[9];
  const float* qn_g = (const float*)d_in[10];
  const float* qn_b = (const float*)d_in[11];
  const float* kn_g = (const float*)d_in[12];
  const float* kn_b = (const float*)d_in[13];

  float* out_attn = (float*)d_out;
  float* out_w    = out_attn + (size_t)BB * LQ * DD;

  constexpr size_t SZ_Q  = (size_t)BB * LQ * DD * 2;
  constexpr size_t SZ_KV = (size_t)BB * LKV * DD * 2;
  constexpr size_t SZ_W  = (size_t)DD * DD * 2;
  char* p = (char*)d_ws;
  u16* hsb  = (u16*)p;              p += SZ_Q;
  u16* casb = (u16*)p;              p += SZ_KV;
  u16* qwb  = (u16*)p;              p += SZ_W;
  u16* kwb  = (u16*)p;              p += SZ_W;
  u16* vwb  = (u16*)p;              p += SZ_W;
  u16* owb  = (u16*)p;              p += SZ_W;
  u16* Qp   = (u16*)p;              p += SZ_Q;
  u16* Kp   = (u16*)p;              p += SZ_KV;
  u16* Vtp  = (u16*)p;              p += SZ_KV;
  u16* AO   = (u16*)p;              p += SZ_Q;

  // 1) all f32->bf16 conversions in one launch
  constexpr unsigned HS4 = BB * LQ * DD / 4;
  constexpr unsigned CAS4 = BB * LKV * DD / 4;
  constexpr unsigned W4 = DD * DD / 4;
  C6 a;
  a.s[0] = (const float4*)hs;  a.d[0] = (ushort4*)hsb;
  a.s[1] = (const float4*)cas; a.d[1] = (ushort4*)casb;
  a.s[2] = (const float4*)q_w; a.d[2] = (ushort4*)qwb;
  a.s[3] = (const float4*)k_w; a.d[3] = (ushort4*)kwb;
  a.s[4] = (const float4*)v_w; a.d[4] = (ushort4*)vwb;
  a.s[5] = (const float4*)o_w; a.d[5] = (ushort4*)owb;
  a.off[0] = 0;
  a.off[1] = HS4;
  a.off[2] = HS4 + CAS4;
  a.off[3] = HS4 + CAS4 + W4;
  a.off[4] = HS4 + CAS4 + 2 * W4;
  a.off[5] = HS4 + CAS4 + 3 * W4;
  a.off[6] = HS4 + CAS4 + 4 * W4;
  k_cvt6<<<dim3((a.off[6] + 255) / 256), dim3(256), 0, stream>>>(a);

  // 2) merged Q/K/V projections (one launch, 2560 blocks)
  k_qkv<<<dim3(2560), dim3(256), 0, stream>>>(
      hsb, casb, qwb, kwb, vwb, q_b, k_b, v_b,
      qn_g, qn_b, kn_g, kn_b, Qp, Kp, Vtp);

  // 3) fused attention (pass A sums + pass B weights/PV)
  k_attn<<<dim3(LQ / 128 * BB * NH), dim3(512), 0, stream>>>(Qp, Kp, Vtp, out_w, AO);

  // 4) O projection -> fp32 into d_out
  k_gemm_nt<1><<<dim3(BB * LQ / 128, DD / 128), dim3(256), 0, stream>>>(
      AO, owb, o_b, nullptr, nullptr, out_attn, BB * LQ, DD, DD);
}